// Round 13
// baseline (70.139 us; speedup 1.0000x reference)
//
#include <hip/hip_runtime.h>
#include <math.h>

#define MIN_NORM 1e-15f
#define BOUND_EPS 1e-5f

typedef __attribute__((ext_vector_type(8))) short short8v;
typedef __attribute__((ext_vector_type(4))) float f32x4;

__device__ __forceinline__ unsigned short f2bf(float f) {
  unsigned int u = __float_as_uint(f);
  unsigned int r = (u + 0x7FFFu + ((u >> 16) & 1u)) >> 16;  // RNE
  return (unsigned short)r;
}
__device__ __forceinline__ unsigned int pack2bf(float a, float b) {
  return (unsigned int)f2bf(a) | ((unsigned int)f2bf(b) << 16);
}

__device__ __forceinline__ float gred16(float v) {  // reduce within aligned 16-lane group
  v += __shfl_xor(v, 1, 64);
  v += __shfl_xor(v, 2, 64);
  v += __shfl_xor(v, 4, 64);
  v += __shfl_xor(v, 8, 64);
  return v;
}
__device__ __forceinline__ float wred64(float v) {
#pragma unroll
  for (int off = 32; off; off >>= 1) v += __shfl_xor(v, off, 64);
  return v;
}
__device__ __forceinline__ float artanh_c(float x) {
  x = fminf(fmaxf(x, -1.f + BOUND_EPS), 1.f - BOUND_EPS);
  return 0.5f * logf((1.f + x) / (1.f - x));
}

// Repack proj -> B-fragment order (bf16), trans -> B-frag order for te @ trans^T.
// projB[((kt*4+nt)*64+l)*8+j] = proj[kt*32+(l>>4)*8+j][nt*16+(l&15)]
// transB[((kt*4+nt)*64+l)*8+j] = trans[nt*16+(l&15)][kt*32+(l>>4)*8+j]
__global__ __launch_bounds__(256) void poincare_prep(
    const float* __restrict__ proj, const float* __restrict__ trans,
    unsigned short* __restrict__ projB, unsigned short* __restrict__ transB) {
  int idx = blockIdx.x * 256 + threadIdx.x;
  if (idx < 49152) {
    int k = idx >> 6, d = idx & 63;
    int kt = k >> 5, t5 = k & 31, lk = t5 >> 3, j = t5 & 7;
    int nt = d >> 4, lr = d & 15;
    int l = lk * 16 + lr;
    projB[((kt * 4 + nt) * 64 + l) * 8 + j] = f2bf(proj[idx]);
  } else if (idx < 49152 + 4096) {
    int i2 = idx - 49152;
    int r = i2 >> 6, c = i2 & 63;
    int nt = r >> 4, lr = r & 15;
    int kt = c >> 5, lk = (c >> 3) & 3, j = c & 7;
    int l = lk * 16 + lr;
    transB[((kt * 4 + nt) * 64 + l) * 8 + j] = f2bf(trans[i2]);
  }
}

// LINEAR-STAGING experiment: 4 M-chunks of 16 rows; each chunk stages its full
// 16x768 region = 48KB of CONTIGUOUS memory (wave w walks rows w*4..w*4+3
// linearly, 1KB/instruction, consecutive instructions continue the run — the
// copy-ubench stream shape). Waves split N (wave w = output cols w*16..+15,
// full K) so no K-split combine. After the M-loop a 17.4KB LDS transpose
// (overlaying the dead staging buffer) restores R8's exact register layout and
// the proven R8 epilogue runs verbatim. Per-element arithmetic order is
// identical to R8 -> absmax 0.0 expected (doubles as a layout check).
__global__ __launch_bounds__(256, 4) void poincare_main(
    const float* __restrict__ seq,
    const unsigned short* __restrict__ projB,
    const unsigned short* __restrict__ transB,
    const float* __restrict__ pos, const float* __restrict__ neg,
    float* __restrict__ wsPart) {
  __shared__ unsigned short stageS[16][776];  // 24832 B; reused as t-transpose (17408 B)
  __shared__ unsigned short teL[4][1024];     // 8 KB epilogue transpose
  __shared__ float partial[4][2];

  const int tid = threadIdx.x;
  const int w = tid >> 6, l = tid & 63;
  const int lr = l & 15, lk = l >> 4;
  const long bIdx = blockIdx.x;

  f32x4 acc4[4];
#pragma unroll
  for (int m = 0; m < 4; ++m) acc4[m] = (f32x4){0.f, 0.f, 0.f, 0.f};

  // ---- M-loop: 4 chunks of 16 rows, full K=768 each ----
#pragma unroll
  for (int m = 0; m < 4; ++m) {
    const float* cBase = seq + (bIdx * 64 + m * 16) * 768;

    // stage: wave w reads rows w*4..w*4+3 of the chunk, each row = 3 x 1KB
    // linear instructions. Whole chunk = 48KB contiguous.
    float4 st[12];
#pragma unroll
    for (int r = 0; r < 4; ++r)
#pragma unroll
      for (int c3 = 0; c3 < 3; ++c3)
        st[r * 3 + c3] = *(const float4*)(cBase + (w * 4 + r) * 768 + c3 * 256 + l * 4);
#pragma unroll
    for (int r = 0; r < 4; ++r)
#pragma unroll
      for (int c3 = 0; c3 < 3; ++c3) {
        float4 v = st[r * 3 + c3];
        *(uint2*)&stageS[w * 4 + r][c3 * 256 + l * 4] =
            make_uint2(pack2bf(v.x, v.y), pack2bf(v.z, v.w));
      }
    __syncthreads();  // all 16 rows staged before any wave computes

    // compute: wave w's 16x16 tile (cols w*16..+15) over K=768.
    // A-frag: row lr, k = kt*32+lk*8 (+pad-776 row stride). B-frag: nt=w slice.
#pragma unroll
    for (int kt = 0; kt < 24; ++kt) {
      short8v bfr = *(const short8v*)(projB + (kt * 4 + w) * 512 + l * 8);
      short8v av = *(const short8v*)&stageS[lr][kt * 32 + lk * 8];
      acc4[m] = __builtin_amdgcn_mfma_f32_16x16x32_bf16(av, bfr, acc4[m], 0, 0, 0);
    }
    __syncthreads();  // compute reads done before next chunk overwrites stageS
  }

  // ---- reassemble t into R8's register layout via LDS (overlays stageS) ----
  // chunk-C layout: lane l holds rows m*16 + lk*4 + i, col w*16 + lr.
  float* tF = (float*)&stageS[0][0];  // [64][68] fp32 = 17408 B
#pragma unroll
  for (int m = 0; m < 4; ++m)
#pragma unroll
    for (int i = 0; i < 4; ++i)
      tF[(m * 16 + lk * 4 + i) * 68 + (w * 16 + lr)] = acc4[m][i];
  __syncthreads();

  f32x4 acc[4];  // R8 layout: wave w rows w*16+lk*4+i, col nt*16+lr
#pragma unroll
  for (int nt = 0; nt < 4; ++nt)
#pragma unroll
    for (int i = 0; i < 4; ++i)
      acc[nt][i] = tF[(w * 16 + lk * 4 + i) * 68 + (nt * 16 + lr)];

  // ======== R8 epilogue, verbatim ========
  // ---- expmap0 in-register ----
  float th[4];
#pragma unroll
  for (int i = 0; i < 4; ++i) {
    float s = acc[0][i] * acc[0][i] + acc[1][i] * acc[1][i] +
              acc[2][i] * acc[2][i] + acc[3][i] * acc[3][i];
    s = gred16(s);
    float n = fmaxf(sqrtf(s), MIN_NORM);
    float t = tanhf(n);
    th[i] = fmaxf(t, MIN_NORM);  // xn = ||te||
    float sc = t / n;
#pragma unroll
    for (int nt = 0; nt < 4; ++nt) acc[nt][i] *= sc;  // te
  }

  // ---- te: C-layout -> A-frag layout via wave-private LDS (XOR-swizzled) ----
  unsigned short* buf = teL[w];
#pragma unroll
  for (int i = 0; i < 4; ++i) {
    int row = lk * 4 + i;
    int sw = (row & 7) << 3;
#pragma unroll
    for (int nt = 0; nt < 4; ++nt) {
      int col = nt * 16 + lr;
      buf[row * 64 + (col ^ sw)] = f2bf(acc[nt][i]);
    }
  }
  __syncthreads();

  // ---- mx = te @ trans^T (K=64) ----
  f32x4 acc2[4];
#pragma unroll
  for (int nt = 0; nt < 4; ++nt) acc2[nt] = (f32x4){0.f, 0.f, 0.f, 0.f};
  const unsigned short* pT = transB + l * 8;
#pragma unroll
  for (int kt = 0; kt < 2; ++kt) {
    short8v a2 = *(const short8v*)&buf[lr * 64 + ((kt * 32 + lk * 8) ^ ((lr & 7) << 3))];
    const unsigned short* pt = pT + kt * 2048;
    short8v c0 = *(const short8v*)(pt);
    short8v c1 = *(const short8v*)(pt + 512);
    short8v c2 = *(const short8v*)(pt + 1024);
    short8v c3 = *(const short8v*)(pt + 1536);
    acc2[0] = __builtin_amdgcn_mfma_f32_16x16x32_bf16(a2, c0, acc2[0], 0, 0, 0);
    acc2[1] = __builtin_amdgcn_mfma_f32_16x16x32_bf16(a2, c1, acc2[1], 0, 0, 0);
    acc2[2] = __builtin_amdgcn_mfma_f32_16x16x32_bf16(a2, c2, acc2[2], 0, 0, 0);
    acc2[3] = __builtin_amdgcn_mfma_f32_16x16x32_bf16(a2, c3, acc2[3], 0, 0, 0);
  }

  // ---- mobius_matvec epilogue + dists, fully in-register ----
  float xp[4], xq[4];
#pragma unroll
  for (int nt = 0; nt < 4; ++nt) {
    xp[nt] = pos[nt * 16 + lr];
    xq[nt] = neg[nt * 16 + lr];
  }
  float x2p = wred64(xp[0] * xp[0] + xp[1] * xp[1] + xp[2] * xp[2] + xp[3] * xp[3]) * 0.25f;
  float x2n = wred64(xq[0] * xq[0] + xq[1] * xq[1] + xq[2] * xq[2] + xq[3] * xq[3]) * 0.25f;

  float distP = 0.f, distN = 0.f;
#pragma unroll
  for (int i = 0; i < 4; ++i) {
    float m0 = acc2[0][i], m1 = acc2[1][i], m2 = acc2[2][i], m3 = acc2[3][i];
    float s = gred16(m0 * m0 + m1 * m1 + m2 * m2 + m3 * m3);
    float mxn = fmaxf(sqrtf(s), MIN_NORM);
    float xn = th[i];
    float rs = tanhf(mxn / xn * artanh_c(xn)) / mxn;
    float r0 = rs * m0, r1 = rs * m1, r2 = rs * m2, r3 = rs * m3;
    float y2 = gred16(r0 * r0 + r1 * r1 + r2 * r2 + r3 * r3);
    float xyP = -gred16(xp[0] * r0 + xp[1] * r1 + xp[2] * r2 + xp[3] * r3);
    float xyN = -gred16(xq[0] * r0 + xq[1] * r1 + xq[2] * r2 + xq[3] * r3);
    {
      float A = 1.f + 2.f * xyP + y2, B = 1.f - x2p;
      float inv = 1.f / fmaxf(1.f + 2.f * xyP + x2p * y2, MIN_NORM);
      float v0 = (B * r0 - A * xp[0]) * inv, v1 = (B * r1 - A * xp[1]) * inv;
      float v2 = (B * r2 - A * xp[2]) * inv, v3 = (B * r3 - A * xp[3]) * inv;
      float nv = fmaxf(sqrtf(gred16(v0 * v0 + v1 * v1 + v2 * v2 + v3 * v3)), MIN_NORM);
      distP += 2.f * artanh_c(nv);
    }
    {
      float A = 1.f + 2.f * xyN + y2, B = 1.f - x2n;
      float inv = 1.f / fmaxf(1.f + 2.f * xyN + x2n * y2, MIN_NORM);
      float v0 = (B * r0 - A * xq[0]) * inv, v1 = (B * r1 - A * xq[1]) * inv;
      float v2 = (B * r2 - A * xq[2]) * inv, v3 = (B * r3 - A * xq[3]) * inv;
      float nv = fmaxf(sqrtf(gred16(v0 * v0 + v1 * v1 + v2 * v2 + v3 * v3)), MIN_NORM);
      distN += 2.f * artanh_c(nv);
    }
  }
  float tP = wred64(distP) * 0.0625f;
  float tN = wred64(distN) * 0.0625f;
  if (l == 0) { partial[w][0] = tP; partial[w][1] = tN; }
  __syncthreads();
  if (tid == 0) {
    wsPart[bIdx * 2 + 0] = partial[0][0] + partial[1][0] + partial[2][0] + partial[3][0];
    wsPart[bIdx * 2 + 1] = partial[0][1] + partial[1][1] + partial[2][1] + partial[3][1];
  }
}

// Deterministic per-batch reduction (separate kernel: stream-ordered, G16-safe).
__global__ __launch_bounds__(128) void poincare_reduce(const float* __restrict__ wsPart,
                                                       float* __restrict__ out) {
  int t = threadIdx.x;
  int b = t >> 1, j = t & 1;
  float s = 0.f;
#pragma unroll
  for (int i = 0; i < 16; ++i) s += wsPart[(b * 16 + i) * 2 + j];
  out[b * 2 + j] = s;
}

extern "C" void kernel_launch(void* const* d_in, const int* in_sizes, int n_in,
                              void* d_out, int out_size, void* d_ws, size_t ws_size,
                              hipStream_t stream) {
  const float* seq = (const float*)d_in[0];
  const float* proj = (const float*)d_in[1];
  const float* trans = (const float*)d_in[2];
  const float* pos = (const float*)d_in[3];
  const float* neg = (const float*)d_in[4];

  unsigned short* projB = (unsigned short*)d_ws;             // 49152 u16 = 98304 B
  unsigned short* transB = projB + 49152;                    // 4096 u16  = 8192 B
  float* wsPart = (float*)((char*)d_ws + 106496);            // 2048 f32  = 8192 B
  float* out = (float*)d_out;

  poincare_prep<<<208, 256, 0, stream>>>(proj, trans, projB, transB);
  poincare_main<<<1024, 256, 0, stream>>>(seq, projB, transB, pos, neg, wsPart);
  poincare_reduce<<<1, 128, 0, stream>>>(wsPart, out);
}

// Round 14
// 50.699 us; speedup vs baseline: 1.3835x; 1.3835x over previous
//
#include <hip/hip_runtime.h>
#include <math.h>

#define MIN_NORM 1e-15f
#define BOUND_EPS 1e-5f

typedef __attribute__((ext_vector_type(8))) short short8v;
typedef __attribute__((ext_vector_type(4))) float f32x4;

__device__ __forceinline__ unsigned short f2bf(float f) {
  unsigned int u = __float_as_uint(f);
  unsigned int r = (u + 0x7FFFu + ((u >> 16) & 1u)) >> 16;  // RNE
  return (unsigned short)r;
}
__device__ __forceinline__ unsigned int pack2bf(float a, float b) {
  return (unsigned int)f2bf(a) | ((unsigned int)f2bf(b) << 16);
}

__device__ __forceinline__ float gred16(float v) {  // reduce within aligned 16-lane group
  v += __shfl_xor(v, 1, 64);
  v += __shfl_xor(v, 2, 64);
  v += __shfl_xor(v, 4, 64);
  v += __shfl_xor(v, 8, 64);
  return v;
}
__device__ __forceinline__ float wred64(float v) {
#pragma unroll
  for (int off = 32; off; off >>= 1) v += __shfl_xor(v, off, 64);
  return v;
}
__device__ __forceinline__ float artanh_c(float x) {
  x = fminf(fmaxf(x, -1.f + BOUND_EPS), 1.f - BOUND_EPS);
  return 0.5f * logf((1.f + x) / (1.f - x));
}

// Repack proj -> B-fragment order (bf16), trans -> B-frag order for te @ trans^T.
// projB[((kt*4+nt)*64+l)*8+j] = proj[kt*32+(l>>4)*8+j][nt*16+(l&15)]
// transB[((kt*4+nt)*64+l)*8+j] = trans[nt*16+(l&15)][kt*32+(l>>4)*8+j]
__global__ __launch_bounds__(256) void poincare_prep(
    const float* __restrict__ proj, const float* __restrict__ trans,
    unsigned short* __restrict__ projB, unsigned short* __restrict__ transB) {
  int idx = blockIdx.x * 256 + threadIdx.x;
  if (idx < 49152) {
    int k = idx >> 6, d = idx & 63;
    int kt = k >> 5, t5 = k & 31, lk = t5 >> 3, j = t5 & 7;
    int nt = d >> 4, lr = d & 15;
    int l = lk * 16 + lr;
    projB[((kt * 4 + nt) * 64 + l) * 8 + j] = f2bf(proj[idx]);
  } else if (idx < 49152 + 4096) {
    int i2 = idx - 49152;
    int r = i2 >> 6, c = i2 & 63;
    int nt = r >> 4, lr = r & 15;
    int kt = c >> 5, lk = (c >> 3) & 3, j = c & 7;
    int l = lk * 16 + lr;
    transB[((kt * 4 + nt) * 64 + l) * 8 + j] = f2bf(trans[i2]);
  }
}

// FINAL (measured-best, R8 structure; 51.1/51.7 us reproduced): 256 threads =
// 4 waves, block-cooperative double-buffered LDS staging of seq in K-chunks of
// 128 floats (bf16 convert at stage time, wave-contiguous 1KB global segments,
// one barrier per chunk), MFMA from LDS A-frags + register B-frags, fully
// in-register Poincare epilogue. 10 structural variants (ILP depth, 8-wave
// K-split, blocks/CU 2..4, wave-private/barrier-free staging, global_load_lds
// DMA, batched-issue, fully-linear M-chunk staging) all landed 51-70 us with
// this structure the floor — composite stream service rate ~4.5 TB/s is the
// practical ceiling for this fused access pattern.
__global__ __launch_bounds__(256, 3) void poincare_main(
    const float* __restrict__ seq,
    const unsigned short* __restrict__ projB,
    const unsigned short* __restrict__ transB,
    const float* __restrict__ pos, const float* __restrict__ neg,
    float* __restrict__ wsPart) {
  __shared__ unsigned short As[2][64][136];  // 128 cols + 8 pad (conflict-optimal)
  __shared__ unsigned short teL[4][16 * 64]; // per-wave transpose buffer
  __shared__ float partial[4][2];

  const int tid = threadIdx.x;
  const int w = tid >> 6, l = tid & 63;
  const int lr = l & 15, lk = l >> 4;
  const long bIdx = blockIdx.x;
  const float* sBase = seq + bIdx * 64 * 768;

  // staging map: instr i, thread t -> row i*8 + (t>>5), cols (t&31)*4..+3
  const int rS = tid >> 5;
  const int cS = (tid & 31) * 4;

  f32x4 acc[4];
#pragma unroll
  for (int nt = 0; nt < 4; ++nt) acc[nt] = (f32x4){0.f, 0.f, 0.f, 0.f};

  // ---- prologue: stage chunk 0 into buffer 0 ----
#pragma unroll
  for (int i = 0; i < 8; ++i) {
    int r = i * 8 + rS;
    float4 v = *(const float4*)(sBase + r * 768 + cS);
    *(uint2*)&As[0][r][cS] = make_uint2(pack2bf(v.x, v.y), pack2bf(v.z, v.w));
  }
  __syncthreads();

  // ---- K loop: 6 chunks x 128 floats ----
#pragma unroll 2
  for (int ch = 0; ch < 6; ++ch) {
    const int cur = ch & 1;

    // (1) B-fragment loads for THIS chunk, issued FIRST: vmcnt retires in-order,
    //     so B must precede the next chunk's HBM stage loads or compute stalls.
    short8v bf[4][4];
#pragma unroll
    for (int ktl = 0; ktl < 4; ++ktl) {
      const unsigned short* pb = projB + (ch * 4 + ktl) * 2048 + l * 8;
      bf[ktl][0] = *(const short8v*)(pb);
      bf[ktl][1] = *(const short8v*)(pb + 512);
      bf[ktl][2] = *(const short8v*)(pb + 1024);
      bf[ktl][3] = *(const short8v*)(pb + 1536);
    }

    // (2) issue next chunk's A stage loads (HBM, wave-contiguous 1KB segments)
    float4 st[8];
    if (ch < 5) {
#pragma unroll
      for (int i = 0; i < 8; ++i) {
        int r = i * 8 + rS;
        st[i] = *(const float4*)(sBase + r * 768 + (ch + 1) * 128 + cS);
      }
    }

    // (3) compute this chunk from LDS A-frags + reg B-frags
#pragma unroll
    for (int ktl = 0; ktl < 4; ++ktl) {
      short8v av = *(const short8v*)&As[cur][w * 16 + lr][ktl * 32 + lk * 8];
      acc[0] = __builtin_amdgcn_mfma_f32_16x16x32_bf16(av, bf[ktl][0], acc[0], 0, 0, 0);
      acc[1] = __builtin_amdgcn_mfma_f32_16x16x32_bf16(av, bf[ktl][1], acc[1], 0, 0, 0);
      acc[2] = __builtin_amdgcn_mfma_f32_16x16x32_bf16(av, bf[ktl][2], acc[2], 0, 0, 0);
      acc[3] = __builtin_amdgcn_mfma_f32_16x16x32_bf16(av, bf[ktl][3], acc[3], 0, 0, 0);
    }

    // (4) write-late: convert + ds_write next chunk into the other buffer
    if (ch < 5) {
#pragma unroll
      for (int i = 0; i < 8; ++i) {
        int r = i * 8 + rS;
        *(uint2*)&As[cur ^ 1][r][cS] =
            make_uint2(pack2bf(st[i].x, st[i].y), pack2bf(st[i].z, st[i].w));
      }
    }
    __syncthreads();
  }

  // C layout: col = nt*16 + lr, row = lk*4 + i. Row-local group = 16 lanes.
  // ---- expmap0 in-register ----
  float th[4];
#pragma unroll
  for (int i = 0; i < 4; ++i) {
    float s = acc[0][i] * acc[0][i] + acc[1][i] * acc[1][i] +
              acc[2][i] * acc[2][i] + acc[3][i] * acc[3][i];
    s = gred16(s);
    float n = fmaxf(sqrtf(s), MIN_NORM);
    float t = tanhf(n);
    th[i] = fmaxf(t, MIN_NORM);  // xn = ||te||
    float sc = t / n;
#pragma unroll
    for (int nt = 0; nt < 4; ++nt) acc[nt][i] *= sc;  // te
  }

  // ---- te: C-layout -> A-frag layout via wave-private LDS (XOR-swizzled) ----
  unsigned short* buf = teL[w];
#pragma unroll
  for (int i = 0; i < 4; ++i) {
    int row = lk * 4 + i;
    int sw = (row & 7) << 3;
#pragma unroll
    for (int nt = 0; nt < 4; ++nt) {
      int col = nt * 16 + lr;
      buf[row * 64 + (col ^ sw)] = f2bf(acc[nt][i]);
    }
  }
  __syncthreads();

  // ---- mx = te @ trans^T (K=64) ----
  f32x4 acc2[4];
#pragma unroll
  for (int nt = 0; nt < 4; ++nt) acc2[nt] = (f32x4){0.f, 0.f, 0.f, 0.f};
  const unsigned short* pT = transB + l * 8;
#pragma unroll
  for (int kt = 0; kt < 2; ++kt) {
    short8v a2 = *(const short8v*)&buf[lr * 64 + ((kt * 32 + lk * 8) ^ ((lr & 7) << 3))];
    const unsigned short* pt = pT + kt * 2048;
    short8v c0 = *(const short8v*)(pt);
    short8v c1 = *(const short8v*)(pt + 512);
    short8v c2 = *(const short8v*)(pt + 1024);
    short8v c3 = *(const short8v*)(pt + 1536);
    acc2[0] = __builtin_amdgcn_mfma_f32_16x16x32_bf16(a2, c0, acc2[0], 0, 0, 0);
    acc2[1] = __builtin_amdgcn_mfma_f32_16x16x32_bf16(a2, c1, acc2[1], 0, 0, 0);
    acc2[2] = __builtin_amdgcn_mfma_f32_16x16x32_bf16(a2, c2, acc2[2], 0, 0, 0);
    acc2[3] = __builtin_amdgcn_mfma_f32_16x16x32_bf16(a2, c3, acc2[3], 0, 0, 0);
  }

  // ---- mobius_matvec epilogue + dists, fully in-register ----
  float xp[4], xq[4];
#pragma unroll
  for (int nt = 0; nt < 4; ++nt) {
    xp[nt] = pos[nt * 16 + lr];
    xq[nt] = neg[nt * 16 + lr];
  }
  float x2p = wred64(xp[0] * xp[0] + xp[1] * xp[1] + xp[2] * xp[2] + xp[3] * xp[3]) * 0.25f;
  float x2n = wred64(xq[0] * xq[0] + xq[1] * xq[1] + xq[2] * xq[2] + xq[3] * xq[3]) * 0.25f;

  float distP = 0.f, distN = 0.f;
#pragma unroll
  for (int i = 0; i < 4; ++i) {
    float m0 = acc2[0][i], m1 = acc2[1][i], m2 = acc2[2][i], m3 = acc2[3][i];
    float s = gred16(m0 * m0 + m1 * m1 + m2 * m2 + m3 * m3);
    float mxn = fmaxf(sqrtf(s), MIN_NORM);
    float xn = th[i];
    float rs = tanhf(mxn / xn * artanh_c(xn)) / mxn;
    float r0 = rs * m0, r1 = rs * m1, r2 = rs * m2, r3 = rs * m3;
    float y2 = gred16(r0 * r0 + r1 * r1 + r2 * r2 + r3 * r3);
    float xyP = -gred16(xp[0] * r0 + xp[1] * r1 + xp[2] * r2 + xp[3] * r3);
    float xyN = -gred16(xq[0] * r0 + xq[1] * r1 + xq[2] * r2 + xq[3] * r3);
    {
      float A = 1.f + 2.f * xyP + y2, B = 1.f - x2p;
      float inv = 1.f / fmaxf(1.f + 2.f * xyP + x2p * y2, MIN_NORM);
      float v0 = (B * r0 - A * xp[0]) * inv, v1 = (B * r1 - A * xp[1]) * inv;
      float v2 = (B * r2 - A * xp[2]) * inv, v3 = (B * r3 - A * xp[3]) * inv;
      float nv = fmaxf(sqrtf(gred16(v0 * v0 + v1 * v1 + v2 * v2 + v3 * v3)), MIN_NORM);
      distP += 2.f * artanh_c(nv);
    }
    {
      float A = 1.f + 2.f * xyN + y2, B = 1.f - x2n;
      float inv = 1.f / fmaxf(1.f + 2.f * xyN + x2n * y2, MIN_NORM);
      float v0 = (B * r0 - A * xq[0]) * inv, v1 = (B * r1 - A * xq[1]) * inv;
      float v2 = (B * r2 - A * xq[2]) * inv, v3 = (B * r3 - A * xq[3]) * inv;
      float nv = fmaxf(sqrtf(gred16(v0 * v0 + v1 * v1 + v2 * v2 + v3 * v3)), MIN_NORM);
      distN += 2.f * artanh_c(nv);
    }
  }
  float tP = wred64(distP) * 0.0625f;
  float tN = wred64(distN) * 0.0625f;
  if (l == 0) { partial[w][0] = tP; partial[w][1] = tN; }
  __syncthreads();
  if (tid == 0) {
    wsPart[bIdx * 2 + 0] = partial[0][0] + partial[1][0] + partial[2][0] + partial[3][0];
    wsPart[bIdx * 2 + 1] = partial[0][1] + partial[1][1] + partial[2][1] + partial[3][1];
  }
}

// Deterministic per-batch reduction (separate kernel: stream-ordered, G16-safe).
__global__ __launch_bounds__(128) void poincare_reduce(const float* __restrict__ wsPart,
                                                       float* __restrict__ out) {
  int t = threadIdx.x;
  int b = t >> 1, j = t & 1;
  float s = 0.f;
#pragma unroll
  for (int i = 0; i < 16; ++i) s += wsPart[(b * 16 + i) * 2 + j];
  out[b * 2 + j] = s;
}

extern "C" void kernel_launch(void* const* d_in, const int* in_sizes, int n_in,
                              void* d_out, int out_size, void* d_ws, size_t ws_size,
                              hipStream_t stream) {
  const float* seq = (const float*)d_in[0];
  const float* proj = (const float*)d_in[1];
  const float* trans = (const float*)d_in[2];
  const float* pos = (const float*)d_in[3];
  const float* neg = (const float*)d_in[4];

  unsigned short* projB = (unsigned short*)d_ws;             // 49152 u16 = 98304 B
  unsigned short* transB = projB + 49152;                    // 4096 u16  = 8192 B
  float* wsPart = (float*)((char*)d_ws + 106496);            // 2048 f32  = 8192 B
  float* out = (float*)d_out;

  poincare_prep<<<208, 256, 0, stream>>>(proj, trans, projB, transB);
  poincare_main<<<1024, 256, 0, stream>>>(seq, projB, transB, pos, neg, wsPart);
  poincare_reduce<<<1, 128, 0, stream>>>(wsPart, out);
}